// Round 6
// baseline (891.536 us; speedup 1.0000x reference)
//
#include <hip/hip_runtime.h>
#include <cstdint>

// Shapes fixed by setup_inputs(): B=8, SQ=SKV=16, H=16, D=128, CACHE=8192.
#define B_     8
#define SQ_    16
#define SKV_   16
#define H_     16
#define D_     128
#define CACHE_ 8192
#define NSPLIT 4   // 128 bh * 4 = 512 blocks = exactly 2 blocks/CU on 256 CUs

typedef __attribute__((ext_vector_type(8))) short bf16x8;
typedef __attribute__((ext_vector_type(4))) float f32x4;

__device__ __forceinline__ unsigned short f2bf(float x) {
  union { float f; unsigned u; } v; v.f = x;
  unsigned r = v.u + 0x7FFFu + ((v.u >> 16) & 1u);  // RNE
  return (unsigned short)(r >> 16);
}

__device__ __forceinline__ bf16x8 pack8(float4 a, float4 b) {
  bf16x8 r;
  r[0] = (short)f2bf(a.x); r[1] = (short)f2bf(a.y);
  r[2] = (short)f2bf(a.z); r[3] = (short)f2bf(a.w);
  r[4] = (short)f2bf(b.x); r[5] = (short)f2bf(b.y);
  r[6] = (short)f2bf(b.z); r[7] = (short)f2bf(b.w);
  return r;
}

// Barrier-free, (almost) LDS-free flash attention.
// 4 independent waves/block, each owns interleaved 32-key macros (stride 128).
// K: global->reg direct in MFMA A-frag layout (lane mq = key row).
// V: global->reg direct in MFMA B-frag layout (lane loads exactly the 64
//    dwords it consumes), split into two 32-VGPR d-halves V0 (nb 0..3) and
//    V1 (nb 4..7). P exchanged via tiny wave-private p_lds (2 ds_write_b64 +
//    1 ds_read_b128 per macro = the only DS ops in the main loop); a
//    sched_barrier(0) pins the cross-lane LDS RAW (compiler alias analysis
//    cannot see lane-crossing deps; HW DS pipe is in-order per wave).
// Register discipline: 4 staging buffers (K0,K1,V0,V1 = 32 VGPR each) with
// FIXED roles, passed by array-reference so SROA keeps them in registers;
// each is consumed then refilled for macro+128 at the same program point
// every iteration -> peak staging 128 VGPR, total ~200 < 256 cap, no spill.
// Prefetch distance ~1 macro-iteration (~25k cyc at BW limit >> 900-cyc HBM
// latency); no __syncthreads in the main loop -> no vmcnt(0) drains.
// Budgets: ~750 VALU/macro/wave (~12% VALUBusy at BW limit), 12 MFMA (~60cy).
// Coalescing: K's paired dwordx4 loads fill complementary 16B chunks at 32B
// stride (L2-merged); V's paired dword loads cover complementary 64B
// half-lines -> HBM traffic 1:1 with the 537MB ideal stream.
// Tail: row indices clamped to L-1 (valid memory); masked scores -> p = 0
// exactly, killing clamped rows. Scale 1/sqrt(D) folded into Q at load.
__global__ __launch_bounds__(256, 2) void attn_partial(
    const float* __restrict__ q, const float* __restrict__ knew,
    const float* __restrict__ vnew, const float* __restrict__ kcache,
    const float* __restrict__ vcache, const int* __restrict__ sidx_p,
    float* __restrict__ o_part, float* __restrict__ m_part,
    float* __restrict__ l_part, float* __restrict__ out,
    int S, int final_mode)
{
  // Main loop: p_lds only (4 waves * 16 rows * 40 shorts; 80B rows -> b128
  // read is a free 2-way bank conflict). Epilogue (after barrier) reuses the
  // pool as part[64][128] f32 + m[64] + l[64].
  __shared__ __align__(16) unsigned char smem_raw[33280];

  const int t    = threadIdx.x;
  const int lane = t & 63;
  const int w    = t >> 6;      // wave 0..3
  const int mq   = lane & 15;
  const int qd   = lane >> 4;   // quad 0..3

  const int bh = blockIdx.x, sp = blockIdx.y;
  const int b  = bh >> 4, hh = bh & 15;
  const int sidx = *sidx_p;
  const int L = sidx + SKV_;
  const int chunk = (L + S - 1) / S;
  const int k0 = sp * chunk;
  const int k1 = min(k0 + chunk, L);

  unsigned short* p_lds = (unsigned short*)smem_raw + w * (16 * 40);

  const float scale = 0.08838834764831845f;  // 1/sqrt(128)

  // ---- Q fragments, global->reg, pre-scaled (B-op: lane mq = q col) ----
  bf16x8 qa[4];
  {
    const float* qp = q + (((long)b * SQ_ + mq) * H_ + hh) * D_ + qd * 8;
    #pragma unroll
    for (int kb = 0; kb < 4; ++kb) {
      float4 a = *(const float4*)(qp + kb * 32);
      float4 c = *(const float4*)(qp + kb * 32 + 4);
      a.x *= scale; a.y *= scale; a.z *= scale; a.w *= scale;
      c.x *= scale; c.y *= scale; c.z *= scale; c.w *= scale;
      qa[kb] = pack8(a, c);
    }
  }

  // Hoisted per-(b,h) bases; key-row stride is H_*D_ floats.
  const int RS = H_ * D_;
  const float* kcb = kcache + ((long)b * CACHE_ * H_ + hh) * D_;
  const float* vcb = vcache + ((long)b * CACHE_ * H_ + hh) * D_;
  const float* knb = knew   + ((long)b * SKV_   * H_ + hh) * D_;
  const float* vnb = vnew   + ((long)b * SKV_   * H_ + hh) * D_;

  auto krow = [&](int l) -> const float* {
    int lc = min(l, L - 1);                 // clamp: masked scores kill it
    return (lc < sidx) ? kcb + (long)lc * RS : knb + (long)(lc - sidx) * RS;
  };
  auto vrow = [&](int l) -> const float* {
    int lc = min(l, L - 1);
    return (lc < sidx) ? vcb + (long)lc * RS : vnb + (long)(lc - sidx) * RS;
  };

  float mrun = -1e30f, lrun = 0.f, alpha = 1.f;
  f32x4 acc[8];
  #pragma unroll
  for (int nb = 0; nb < 8; ++nb) acc[nb] = (f32x4){0.f, 0.f, 0.f, 0.f};

  // K loads for a 16-key half (A-frag: lane mq = key row, k = qd*8+j).
  auto issueK = [&](int hb, float4 (&kx)[8]) {
    const float* kp = krow(hb + mq) + qd * 8;
    #pragma unroll
    for (int kb = 0; kb < 4; ++kb) {
      kx[2 * kb]     = *(const float4*)(kp + kb * 32);
      kx[2 * kb + 1] = *(const float4*)(kp + kb * 32 + 4);
    }
  };
  // V loads for one d-half of a 32-key macro, direct B-frag layout:
  // vx[nb*8+j] = V[base + qd*8 + j][(nbase+nb)*16 + mq], nb = 0..3.
  auto issueV = [&](int base, int nbase, float (&vx)[32]) {
    #pragma unroll
    for (int j = 0; j < 8; ++j) {
      const float* vp = vrow(base + qd * 8 + j) + nbase * 16 + mq;
      #pragma unroll
      for (int nb = 0; nb < 4; ++nb)
        vx[nb * 8 + j] = vp[nb * 16];
    }
  };

  // QK^T for one 16-key half (swapped: A=K, B=Q -> C row = key qd*4+r,
  // col = query mq), online softmax (max from half 0 only; half 1 defers
  // to it -> p may exceed 1 by ~e^few, harmless in f32/bf16), P -> p_lds.
  auto qk_half = [&](int hb, int hsel, const float4 (&kx)[8], bool first) {
    f32x4 sc = {0.f, 0.f, 0.f, 0.f};
    #pragma unroll
    for (int kb = 0; kb < 4; ++kb) {
      bf16x8 kf = pack8(kx[2 * kb], kx[2 * kb + 1]);
      sc = __builtin_amdgcn_mfma_f32_16x16x32_bf16(kf, qa[kb], sc, 0, 0, 0);
    }
    float s[4];
    #pragma unroll
    for (int r = 0; r < 4; ++r) {
      int key = hb + qd * 4 + r;
      s[r] = (key < k1) ? sc[r] : -1e30f;   // Q pre-scaled
    }
    if (first) {
      float tmax = fmaxf(fmaxf(s[0], s[1]), fmaxf(s[2], s[3]));
      tmax = fmaxf(tmax, __shfl_xor(tmax, 16));   // reduce across qd groups
      tmax = fmaxf(tmax, __shfl_xor(tmax, 32));   // -> per-query (mq) max
      float mnew = fmaxf(mrun, tmax);
      alpha = __expf(mrun - mnew);
      mrun  = mnew;
      lrun *= alpha;
    }
    float ts = 0.f;
    unsigned short pb[4];
    #pragma unroll
    for (int r = 0; r < 4; ++r) {
      float pe = __expf(s[r] - mrun);   // masked keys -> exactly 0
      ts += pe;
      pb[r] = f2bf(pe);
    }
    ts += __shfl_xor(ts, 16);
    ts += __shfl_xor(ts, 32);
    lrun += ts;
    *(ushort4*)&p_lds[mq * 40 + hsel * 16 + qd * 4] =
        make_ushort4(pb[0], pb[1], pb[2], pb[3]);
  };

  // One PV d-half: 4 MFMAs. pa: A-frag P (row = query mq, k = key qd*8+j).
  auto pv_half = [&](const float (&vx)[32], const bf16x8& pa, int nbase) {
    #pragma unroll
    for (int nb = 0; nb < 4; ++nb) {
      bf16x8 vb;
      #pragma unroll
      for (int j = 0; j < 8; ++j) vb[j] = (short)f2bf(vx[nb * 8 + j]);
      acc[nbase + nb] =
          __builtin_amdgcn_mfma_f32_16x16x32_bf16(pa, vb, acc[nbase + nb], 0, 0, 0);
    }
  };

  // ---- main loop: fixed-role buffers, consume->refill at same point ----
  const int wbase = k0 + w * 32;
  if (wbase < k1) {
    float4 K0[8], K1[8];
    float  V0[32], V1[32];
    issueK(wbase,      K0);
    issueK(wbase + 16, K1);
    issueV(wbase, 0, V0);
    issueV(wbase, 4, V1);
    for (int base = wbase; base < k1; base += 128) {
      const bool more = (base + 128 < k1);   // wave-uniform
      qk_half(base, 0, K0, true);
      if (more) issueK(base + 128, K0);
      qk_half(base + 16, 1, K1, false);
      if (more) issueK(base + 144, K1);
      // Cross-lane LDS RAW: both halves' p-writes must precede the pa read.
      // Compiler alias analysis can't see lane-crossing deps -> pin order;
      // DS pipe is in-order per wave, lgkmcnt on pa's data inserted by hipcc.
      __builtin_amdgcn_sched_barrier(0);
      bf16x8 pa = *(const bf16x8*)&p_lds[mq * 40 + qd * 8];
      float ar[4];
      #pragma unroll
      for (int r = 0; r < 4; ++r) ar[r] = __shfl(alpha, qd * 4 + r);
      #pragma unroll
      for (int nb = 0; nb < 8; ++nb)
        #pragma unroll
        for (int r = 0; r < 4; ++r) acc[nb][r] *= ar[r];
      pv_half(V0, pa, 0);
      if (more) issueV(base + 128, 0, V0);
      pv_half(V1, pa, 4);
      if (more) issueV(base + 128, 4, V1);
    }
  }

  // ---- epilogue: combine the 4 waves' partials (2 barriers total) ----
  __syncthreads();  // all waves done with p_lds; pool repurposed below
  {
    float* part = (float*)smem_raw;            // [64][128]  (wave*16+q, d)
    float* mls  = (float*)(smem_raw + 32768);  // m[64], l[64]
    #pragma unroll
    for (int nb = 0; nb < 8; ++nb)
      #pragma unroll
      for (int r = 0; r < 4; ++r)
        part[(w * 16 + qd * 4 + r) * 128 + nb * 16 + mq] = acc[nb][r];
    if (qd == 0) { mls[w * 16 + mq] = mrun; mls[64 + w * 16 + mq] = lrun; }
  }
  __syncthreads();
  {
    const float* part = (const float*)smem_raw;
    const float* mv   = (const float*)(smem_raw + 32768);
    const float* lv   = mv + 64;
    int qrow = t >> 4, d0 = (t & 15) * 8;
    float M = fmaxf(fmaxf(mv[qrow], mv[16 + qrow]),
                    fmaxf(mv[32 + qrow], mv[48 + qrow]));
    float wt[4], den = 0.f;
    #pragma unroll
    for (int u = 0; u < 4; ++u) {
      wt[u] = __expf(mv[u * 16 + qrow] - M);   // idle wave: m=-1e30 -> wt=0
      den += wt[u] * lv[u * 16 + qrow];
    }
    float num[8];
    #pragma unroll
    for (int j = 0; j < 8; ++j) num[j] = 0.f;
    #pragma unroll
    for (int u = 0; u < 4; ++u) {
      const float* pr = &part[(u * 16 + qrow) * 128 + d0];
      float4 x0 = *(const float4*)pr;
      float4 x1 = *(const float4*)(pr + 4);
      num[0] += wt[u] * x0.x; num[1] += wt[u] * x0.y;
      num[2] += wt[u] * x0.z; num[3] += wt[u] * x0.w;
      num[4] += wt[u] * x1.x; num[5] += wt[u] * x1.y;
      num[6] += wt[u] * x1.z; num[7] += wt[u] * x1.w;
    }
    if (final_mode) {
      float inv = 1.f / den;
      float* op = out + (((long)b * SQ_ + qrow) * H_ + hh) * D_ + d0;
      *(float4*)op       = make_float4(num[0] * inv, num[1] * inv, num[2] * inv, num[3] * inv);
      *(float4*)(op + 4) = make_float4(num[4] * inv, num[5] * inv, num[6] * inv, num[7] * inv);
    } else {
      long pbase = ((long)bh * S + sp) * 16;
      float* op = o_part + (pbase + qrow) * 128 + d0;
      *(float4*)op       = make_float4(num[0], num[1], num[2], num[3]);
      *(float4*)(op + 4) = make_float4(num[4], num[5], num[6], num[7]);
      if ((t & 15) == 0) { m_part[pbase + qrow] = M; l_part[pbase + qrow] = den; }
    }
  }
}

__global__ void attn_combine(const float* __restrict__ o_part,
                             const float* __restrict__ m_part,
                             const float* __restrict__ l_part,
                             float* __restrict__ out, int S)
{
  int row = blockIdx.x;            // bh*16 + i
  int bh = row >> 4, i = row & 15;
  int b = bh >> 4, h = bh & 15;
  int d = threadIdx.x;             // 0..127
  float mg = -1e30f;
  for (int s = 0; s < S; ++s)
    mg = fmaxf(mg, m_part[((long)bh * S + s) * 16 + i]);
  float num = 0.f, den = 0.f;
  for (int s = 0; s < S; ++s) {
    long pi = ((long)bh * S + s) * 16 + i;
    float ws = __expf(m_part[pi] - mg);
    den += ws * l_part[pi];
    num += ws * o_part[pi * 128 + d];
  }
  out[(((long)b * SQ_ + i) * H_ + h) * (long)D_ + d] = num / den;
}

extern "C" void kernel_launch(void* const* d_in, const int* in_sizes, int n_in,
                              void* d_out, int out_size, void* d_ws, size_t ws_size,
                              hipStream_t stream)
{
  const float* q  = (const float*)d_in[0];
  const float* k  = (const float*)d_in[1];
  const float* v  = (const float*)d_in[2];
  const float* kc = (const float*)d_in[3];
  const float* vc = (const float*)d_in[4];
  const int* sidx = (const int*)d_in[5];
  float* out = (float*)d_out;

  const int S = NSPLIT;
  const size_t need = (size_t)S * B_ * H_ * (16 * 128 + 32) * sizeof(float);
  if (ws_size >= need) {
    float* o_part = (float*)d_ws;
    float* m_part = o_part + (size_t)S * B_ * H_ * 16 * 128;
    float* l_part = m_part + (size_t)S * B_ * H_ * 16;
    attn_partial<<<dim3(B_ * H_, S), 256, 0, stream>>>(
        q, k, v, kc, vc, sidx, o_part, m_part, l_part, out, S, 0);
    attn_combine<<<dim3(B_ * H_ * SQ_), 128, 0, stream>>>(
        o_part, m_part, l_part, out, S);
  } else {
    attn_partial<<<dim3(B_ * H_, 1), 256, 0, stream>>>(
        q, k, v, kc, vc, sidx, nullptr, nullptr, nullptr, out, 1, 1);
  }
}